// Round 1
// baseline (409.321 us; speedup 1.0000x reference)
//
#include <hip/hip_runtime.h>
#include <math.h>

#define NUM_GRAPHS 1024
#define IN_F 256
#define HID 512

__device__ __forceinline__ int lower_bound_i(const int* __restrict__ b, int n, int v) {
    int lo = 0, hi = n;
    while (lo < hi) {
        int mid = (lo + hi) >> 1;
        if (b[mid] < v) lo = mid + 1; else hi = mid;
    }
    return lo;
}

// ---------------- Kernel 1: segment sum/mean/max pooling ----------------
// One block per graph; batch is sorted so boundaries come from binary search.
// thread = feature column -> fully coalesced 4B/lane row reads.
__global__ __launch_bounds__(256) void pool_kernel(
    const float* __restrict__ x, const int* __restrict__ batch, int N,
    float* __restrict__ sum_pool, float* __restrict__ mean_pool,
    float* __restrict__ max_pool)
{
    int g = blockIdx.x;
    __shared__ int sb[2];
    if (threadIdx.x < 2) sb[threadIdx.x] = lower_bound_i(batch, N, g + (int)threadIdx.x);
    __syncthreads();
    int start = sb[0], end = sb[1];
    int f = threadIdx.x;
    const float* xp = x + f;
    float s = 0.f;
    float mx = -INFINITY;
    int r = start;
    for (; r + 8 <= end; r += 8) {   // 8 outstanding loads per wave
        float v0 = xp[(size_t)(r+0)*IN_F];
        float v1 = xp[(size_t)(r+1)*IN_F];
        float v2 = xp[(size_t)(r+2)*IN_F];
        float v3 = xp[(size_t)(r+3)*IN_F];
        float v4 = xp[(size_t)(r+4)*IN_F];
        float v5 = xp[(size_t)(r+5)*IN_F];
        float v6 = xp[(size_t)(r+6)*IN_F];
        float v7 = xp[(size_t)(r+7)*IN_F];
        s += ((v0+v1)+(v2+v3)) + ((v4+v5)+(v6+v7));
        mx = fmaxf(mx, fmaxf(fmaxf(fmaxf(v0,v1), fmaxf(v2,v3)),
                             fmaxf(fmaxf(v4,v5), fmaxf(v6,v7))));
    }
    for (; r < end; ++r) {
        float v = xp[(size_t)r*IN_F];
        s += v; mx = fmaxf(mx, v);
    }
    int cnt = end - start;
    float mean = s / fmaxf((float)cnt, 1.0f);
    if (cnt == 0) mx = 0.f;      // reference: where(counts>0, max, 0)
    int o = g*IN_F + f;
    sum_pool[o]  = s;
    mean_pool[o] = mean;
    max_pool[o]  = mx;
}

// ---------------- Kernel 2: three transform GEMMs ----------------
// repr_z = pool_z @ W_z + b_z   [1024,256]@[256,512], z = blockIdx.z in {mean,max,sum}
#define BM 64
#define BN 32
#define BKK 32
__global__ __launch_bounds__(256) void transform_gemm(
    const float* __restrict__ p_mean, const float* __restrict__ p_max, const float* __restrict__ p_sum,
    const float* __restrict__ Wm, const float* __restrict__ bm_,
    const float* __restrict__ Wx, const float* __restrict__ bx_,
    const float* __restrict__ Wsm, const float* __restrict__ bs_,
    float* __restrict__ r_mean, float* __restrict__ r_max, float* __restrict__ r_sum)
{
    int z = blockIdx.z;
    const float* P    = (z==0) ? p_mean : (z==1) ? p_max : p_sum;
    const float* W    = (z==0) ? Wm     : (z==1) ? Wx    : Wsm;
    const float* bias = (z==0) ? bm_    : (z==1) ? bx_   : bs_;
    float* R          = (z==0) ? r_mean : (z==1) ? r_max : r_sum;

    __shared__ float As[BKK][BM+1];  // k-major, +1 pad breaks write conflicts
    __shared__ float Bs[BKK][BN+1];
    int tid = threadIdx.x;
    int bm0 = blockIdx.y * BM;
    int bn0 = blockIdx.x * BN;
    int ty = tid >> 4, tx = tid & 15;
    int m0 = ty * 4, n0 = tx * 2;
    float acc[4][2] = {};

    for (int kc = 0; kc < IN_F; kc += BKK) {
        #pragma unroll
        for (int i = 0; i < 8; ++i) {       // A tile 64x32
            int idx = tid + i*256;
            int rr = idx >> 5, cc = idx & 31;
            As[cc][rr] = P[(bm0 + rr)*IN_F + kc + cc];
        }
        #pragma unroll
        for (int i = 0; i < 4; ++i) {       // B tile 32x32
            int idx = tid + i*256;
            int rr = idx >> 5, cc = idx & 31;
            Bs[rr][cc] = W[(kc + rr)*HID + bn0 + cc];
        }
        __syncthreads();
        #pragma unroll
        for (int k = 0; k < BKK; ++k) {
            float a0 = As[k][m0+0], a1 = As[k][m0+1];
            float a2 = As[k][m0+2], a3 = As[k][m0+3];
            float b0 = Bs[k][n0+0], b1 = Bs[k][n0+1];
            acc[0][0] += a0*b0; acc[0][1] += a0*b1;
            acc[1][0] += a1*b0; acc[1][1] += a1*b1;
            acc[2][0] += a2*b0; acc[2][1] += a2*b1;
            acc[3][0] += a3*b0; acc[3][1] += a3*b1;
        }
        __syncthreads();
    }
    #pragma unroll
    for (int i = 0; i < 4; ++i) {
        #pragma unroll
        for (int j = 0; j < 2; ++j) {
            int row = bm0 + m0 + i, col = bn0 + n0 + j;
            R[(size_t)row*HID + col] = acc[i][j] + bias[col];
        }
    }
}

// ---------------- Kernel 3: gated fusion ----------------
// One block per graph: 3 dot-products (512) -> sigmoid -> softmax -> weighted sum.
__global__ __launch_bounds__(256) void gate_fuse(
    const float* __restrict__ r_mean, const float* __restrict__ r_max, const float* __restrict__ r_sum,
    const float* __restrict__ gwm, const float* __restrict__ gbm,
    const float* __restrict__ gwx, const float* __restrict__ gbx,
    const float* __restrict__ gws, const float* __restrict__ gbs,
    float* __restrict__ pooled)
{
    int g = blockIdx.x;
    int tid = threadIdx.x;
    size_t base = (size_t)g * HID;
    int h0 = tid, h1 = tid + 256;
    float m0 = r_mean[base+h0], m1 = r_mean[base+h1];
    float x0 = r_max[base+h0],  x1 = r_max[base+h1];
    float s0 = r_sum[base+h0],  s1 = r_sum[base+h1];
    float pm = m0*gwm[h0] + m1*gwm[h1];
    float px = x0*gwx[h0] + x1*gwx[h1];
    float ps = s0*gws[h0] + s1*gws[h1];
    #pragma unroll
    for (int off = 32; off > 0; off >>= 1) {   // wave64 butterfly
        pm += __shfl_xor(pm, off, 64);
        px += __shfl_xor(px, off, 64);
        ps += __shfl_xor(ps, off, 64);
    }
    __shared__ float red[3][4];
    __shared__ float wgt[3];
    int wv = tid >> 6, lane = tid & 63;
    if (lane == 0) { red[0][wv] = pm; red[1][wv] = px; red[2][wv] = ps; }
    __syncthreads();
    if (tid == 0) {
        float dm  = red[0][0]+red[0][1]+red[0][2]+red[0][3] + gbm[0];
        float dx  = red[1][0]+red[1][1]+red[1][2]+red[1][3] + gbx[0];
        float dsv = red[2][0]+red[2][1]+red[2][2]+red[2][3] + gbs[0];
        float sm = 1.f/(1.f+expf(-dm));
        float sx = 1.f/(1.f+expf(-dx));
        float ss = 1.f/(1.f+expf(-dsv));
        float em = expf(sm), ex = expf(sx), es = expf(ss);
        float inv = 1.f/(em+ex+es);
        wgt[0] = em*inv; wgt[1] = ex*inv; wgt[2] = es*inv;
    }
    __syncthreads();
    float wm = wgt[0], wxx = wgt[1], wss = wgt[2];
    pooled[base+h0] = wm*m0 + wxx*x0 + wss*s0;
    pooled[base+h1] = wm*m1 + wxx*x1 + wss*s1;
}

// ---------------- Kernel 4: output projection + layernorm ----------------
// 4 graphs per block; thread = output feature; then per-wave LN over 256 feats.
#define EM 4
__global__ __launch_bounds__(256) void outproj_ln(
    const float* __restrict__ pooled, const float* __restrict__ Wout, const float* __restrict__ bout,
    const float* __restrict__ gamma, const float* __restrict__ beta, float* __restrict__ out)
{
    int gbase = blockIdx.x * EM;
    int tid = threadIdx.x;
    __shared__ float Ps[EM][HID];   // 8 KB
    __shared__ float Es[EM][IN_F];  // 4 KB
    const float4* pp = (const float4*)(pooled + (size_t)gbase * HID);
    float4* ps4 = (float4*)&Ps[0][0];
    ps4[tid]       = pp[tid];
    ps4[tid + 256] = pp[tid + 256];
    __syncthreads();
    float acc0=0.f, acc1=0.f, acc2=0.f, acc3=0.f;
    int f = tid;
    #pragma unroll 4
    for (int k = 0; k < HID; ++k) {
        float w = Wout[(size_t)k*IN_F + f];   // coalesced; Ps reads are LDS broadcast
        acc0 += Ps[0][k]*w;
        acc1 += Ps[1][k]*w;
        acc2 += Ps[2][k]*w;
        acc3 += Ps[3][k]*w;
    }
    float bo = bout[f];
    Es[0][f] = acc0+bo; Es[1][f] = acc1+bo; Es[2][f] = acc2+bo; Es[3][f] = acc3+bo;
    __syncthreads();
    int w = tid >> 6;      // wave -> row
    int lane = tid & 63;
    float v0 = Es[w][lane], v1 = Es[w][lane+64], v2 = Es[w][lane+128], v3 = Es[w][lane+192];
    float s  = v0+v1+v2+v3;
    float sq = v0*v0+v1*v1+v2*v2+v3*v3;
    #pragma unroll
    for (int off = 32; off > 0; off >>= 1) {
        s  += __shfl_xor(s, off, 64);
        sq += __shfl_xor(sq, off, 64);
    }
    float mu  = s * (1.0f/IN_F);
    float var = sq * (1.0f/IN_F) - mu*mu;
    float rs  = rsqrtf(var + 1e-5f);
    float* orow = out + (size_t)(gbase + w) * IN_F;
    orow[lane]     = (v0-mu)*rs*gamma[lane]     + beta[lane];
    orow[lane+64]  = (v1-mu)*rs*gamma[lane+64]  + beta[lane+64];
    orow[lane+128] = (v2-mu)*rs*gamma[lane+128] + beta[lane+128];
    orow[lane+192] = (v3-mu)*rs*gamma[lane+192] + beta[lane+192];
}

extern "C" void kernel_launch(void* const* d_in, const int* in_sizes, int n_in,
                              void* d_out, int out_size, void* d_ws, size_t ws_size,
                              hipStream_t stream)
{
    const float* x        = (const float*)d_in[0];
    const int*   batch    = (const int*)d_in[1];
    const float* W_mean   = (const float*)d_in[2];
    const float* b_mean   = (const float*)d_in[3];
    const float* W_max    = (const float*)d_in[4];
    const float* b_max    = (const float*)d_in[5];
    const float* W_sum    = (const float*)d_in[6];
    const float* b_sum    = (const float*)d_in[7];
    const float* g_mean_w = (const float*)d_in[8];
    const float* g_mean_b = (const float*)d_in[9];
    const float* g_max_w  = (const float*)d_in[10];
    const float* g_max_b  = (const float*)d_in[11];
    const float* g_sum_w  = (const float*)d_in[12];
    const float* g_sum_b  = (const float*)d_in[13];
    const float* W_out    = (const float*)d_in[14];
    const float* b_out    = (const float*)d_in[15];
    const float* ln_gamma = (const float*)d_in[16];
    const float* ln_beta  = (const float*)d_in[17];
    float* out = (float*)d_out;
    int N = in_sizes[1];   // 200000 nodes

    // workspace layout (floats): 3 pools [1024,256], 3 reprs [1024,512], pooled [1024,512]
    float* ws        = (float*)d_ws;
    float* sum_pool  = ws;
    float* mean_pool = ws + (size_t)NUM_GRAPHS*IN_F;
    float* max_pool  = ws + (size_t)2*NUM_GRAPHS*IN_F;
    float* r_mean    = ws + (size_t)3*NUM_GRAPHS*IN_F;
    float* r_max     = r_mean + (size_t)NUM_GRAPHS*HID;
    float* r_sum     = r_max  + (size_t)NUM_GRAPHS*HID;
    float* pooled    = r_sum  + (size_t)NUM_GRAPHS*HID;

    pool_kernel<<<NUM_GRAPHS, 256, 0, stream>>>(x, batch, N, sum_pool, mean_pool, max_pool);

    dim3 gridC(HID/BN, NUM_GRAPHS/BM, 3);   // (16,16,3)
    transform_gemm<<<gridC, 256, 0, stream>>>(mean_pool, max_pool, sum_pool,
                                              W_mean, b_mean, W_max, b_max, W_sum, b_sum,
                                              r_mean, r_max, r_sum);

    gate_fuse<<<NUM_GRAPHS, 256, 0, stream>>>(r_mean, r_max, r_sum,
                                              g_mean_w, g_mean_b, g_max_w, g_max_b,
                                              g_sum_w, g_sum_b, pooled);

    outproj_ln<<<NUM_GRAPHS/EM, 256, 0, stream>>>(pooled, W_out, b_out, ln_gamma, ln_beta, out);
}

// Round 2
// 404.515 us; speedup vs baseline: 1.0119x; 1.0119x over previous
//
#include <hip/hip_runtime.h>
#include <math.h>

#define NUM_GRAPHS 1024
#define IN_F 256
#define HID 512

__device__ __forceinline__ int lower_bound_i(const int* __restrict__ b, int n, int v) {
    int lo = 0, hi = n;
    while (lo < hi) {
        int mid = (lo + hi) >> 1;
        if (b[mid] < v) lo = mid + 1; else hi = mid;
    }
    return lo;
}

// ---------------- K1: segment sum/mean/max pooling ----------------
// One block per graph. Wave w handles rows start+w, start+w+4, ... ; each lane
// holds 4 features via float4 -> one wave-instr reads a full 1KB row (fully
// coalesced). Cross-wave combine through LDS.
__global__ __launch_bounds__(256) void pool_kernel(
    const float* __restrict__ x, const int* __restrict__ batch, int N,
    float* __restrict__ sum_pool, float* __restrict__ mean_pool,
    float* __restrict__ max_pool)
{
    int g = blockIdx.x;
    __shared__ int sb[2];
    if (threadIdx.x < 2) sb[threadIdx.x] = lower_bound_i(batch, N, g + (int)threadIdx.x);
    __syncthreads();
    int start = sb[0], end = sb[1];
    int cnt = end - start;
    int w = threadIdx.x >> 6, lane = threadIdx.x & 63;
    const float4* x4 = (const float4*)x;     // row r lives at x4[r*64 + lane]
    float4 s = make_float4(0.f, 0.f, 0.f, 0.f);
    float4 m = make_float4(-INFINITY, -INFINITY, -INFINITY, -INFINITY);
    int r = start + w;
    for (; r + 12 < end; r += 16) {          // 4 rows (4KB) in flight per wave
        float4 v0 = x4[(size_t)(r     )*64 + lane];
        float4 v1 = x4[(size_t)(r +  4)*64 + lane];
        float4 v2 = x4[(size_t)(r +  8)*64 + lane];
        float4 v3 = x4[(size_t)(r + 12)*64 + lane];
        s.x += (v0.x+v1.x)+(v2.x+v3.x); s.y += (v0.y+v1.y)+(v2.y+v3.y);
        s.z += (v0.z+v1.z)+(v2.z+v3.z); s.w += (v0.w+v1.w)+(v2.w+v3.w);
        m.x = fmaxf(m.x, fmaxf(fmaxf(v0.x,v1.x), fmaxf(v2.x,v3.x)));
        m.y = fmaxf(m.y, fmaxf(fmaxf(v0.y,v1.y), fmaxf(v2.y,v3.y)));
        m.z = fmaxf(m.z, fmaxf(fmaxf(v0.z,v1.z), fmaxf(v2.z,v3.z)));
        m.w = fmaxf(m.w, fmaxf(fmaxf(v0.w,v1.w), fmaxf(v2.w,v3.w)));
    }
    for (; r < end; r += 4) {
        float4 v = x4[(size_t)r*64 + lane];
        s.x += v.x; s.y += v.y; s.z += v.z; s.w += v.w;
        m.x = fmaxf(m.x, v.x); m.y = fmaxf(m.y, v.y);
        m.z = fmaxf(m.z, v.z); m.w = fmaxf(m.w, v.w);
    }
    __shared__ float4 Ls[4][64];
    __shared__ float4 Lm[4][64];
    Ls[w][lane] = s; Lm[w][lane] = m;
    __syncthreads();
    if (w == 0) {
        float4 s0 = Ls[0][lane], s1 = Ls[1][lane], s2 = Ls[2][lane], s3 = Ls[3][lane];
        float4 m0 = Lm[0][lane], m1 = Lm[1][lane], m2 = Lm[2][lane], m3 = Lm[3][lane];
        float4 st, mt;
        st.x = (s0.x+s1.x)+(s2.x+s3.x); st.y = (s0.y+s1.y)+(s2.y+s3.y);
        st.z = (s0.z+s1.z)+(s2.z+s3.z); st.w = (s0.w+s1.w)+(s2.w+s3.w);
        mt.x = fmaxf(fmaxf(m0.x,m1.x), fmaxf(m2.x,m3.x));
        mt.y = fmaxf(fmaxf(m0.y,m1.y), fmaxf(m2.y,m3.y));
        mt.z = fmaxf(fmaxf(m0.z,m1.z), fmaxf(m2.z,m3.z));
        mt.w = fmaxf(fmaxf(m0.w,m1.w), fmaxf(m2.w,m3.w));
        float inv = 1.0f / fmaxf((float)cnt, 1.0f);
        float4 me = make_float4(st.x*inv, st.y*inv, st.z*inv, st.w*inv);
        if (cnt == 0) mt = make_float4(0.f, 0.f, 0.f, 0.f);
        size_t o = (size_t)g*64 + lane;
        ((float4*)sum_pool)[o]  = st;
        ((float4*)mean_pool)[o] = me;
        ((float4*)max_pool)[o]  = mt;
    }
}

// ---------------- K2: three transform GEMMs ----------------
// repr_z = pool_z @ W_z + b_z : [1024,256]@[256,512], z = blockIdx.z
// 64x64 tile, BK=16, 4x4 per-thread tile, ds_read_b128 fragments (2 B/MAC).
#define BM 64
#define BN 64
#define BK 16
#define LDA 68   // padded stride: 272 B = 17*16 keeps b128 alignment; <=2-way banks
__global__ __launch_bounds__(256) void transform_gemm(
    const float* __restrict__ p_mean, const float* __restrict__ p_max, const float* __restrict__ p_sum,
    const float* __restrict__ Wm, const float* __restrict__ bm_,
    const float* __restrict__ Wx, const float* __restrict__ bx_,
    const float* __restrict__ Wsm, const float* __restrict__ bs_,
    float* __restrict__ r_mean, float* __restrict__ r_max, float* __restrict__ r_sum)
{
    int z = blockIdx.z;
    const float* P    = (z==0) ? p_mean : (z==1) ? p_max : p_sum;
    const float* W    = (z==0) ? Wm     : (z==1) ? Wx    : Wsm;
    const float* bias = (z==0) ? bm_    : (z==1) ? bx_   : bs_;
    float* R          = (z==0) ? r_mean : (z==1) ? r_max : r_sum;

    __shared__ float As[BK][LDA];   // k-major: As[k][m]
    __shared__ float Bs[BK][LDA];   // Bs[k][n]
    int tid = threadIdx.x;
    int bm0 = blockIdx.y * BM;
    int bn0 = blockIdx.x * BN;
    int tx = tid & 15, ty = tid >> 4;          // 16x16 threads, 4x4 tile each
    int arow = tid >> 2, akq = (tid & 3) * 4;  // A stage: row 0..63, k-quad
    int brow = tid >> 4, bn4 = (tid & 15) * 4; // B stage: k-row 0..15, n-quad
    float acc[4][4] = {};

    for (int kc = 0; kc < IN_F; kc += BK) {
        float4 av = *(const float4*)&P[(size_t)(bm0 + arow)*IN_F + kc + akq];
        float4 bv = *(const float4*)&W[(size_t)(kc + brow)*HID + bn0 + bn4];
        As[akq+0][arow] = av.x; As[akq+1][arow] = av.y;
        As[akq+2][arow] = av.z; As[akq+3][arow] = av.w;
        *(float4*)&Bs[brow][bn4] = bv;
        __syncthreads();
        #pragma unroll
        for (int k = 0; k < BK; ++k) {
            float4 a = *(const float4*)&As[k][ty*4];   // 4 addrs/wave, broadcast
            float4 b = *(const float4*)&Bs[k][tx*4];   // 16 addrs, 2-way = free
            acc[0][0] += a.x*b.x; acc[0][1] += a.x*b.y; acc[0][2] += a.x*b.z; acc[0][3] += a.x*b.w;
            acc[1][0] += a.y*b.x; acc[1][1] += a.y*b.y; acc[1][2] += a.y*b.z; acc[1][3] += a.y*b.w;
            acc[2][0] += a.z*b.x; acc[2][1] += a.z*b.y; acc[2][2] += a.z*b.z; acc[2][3] += a.z*b.w;
            acc[3][0] += a.w*b.x; acc[3][1] += a.w*b.y; acc[3][2] += a.w*b.z; acc[3][3] += a.w*b.w;
        }
        __syncthreads();
    }
    float4 b4 = *(const float4*)&bias[bn0 + tx*4];
    #pragma unroll
    for (int i = 0; i < 4; ++i) {
        float4 o = make_float4(acc[i][0]+b4.x, acc[i][1]+b4.y, acc[i][2]+b4.z, acc[i][3]+b4.w);
        *(float4*)&R[(size_t)(bm0 + ty*4 + i)*HID + bn0 + tx*4] = o;
    }
}

// ---------------- K3: gates + fusion + output projection + layernorm ----------------
// 4 graphs per block. Stage repr rows in LDS; wave w computes graph w's three
// gate dots + softmax; build pooled in LDS; GEMM with float4 broadcast reads;
// per-wave layernorm epilogue.
#define EM 4
__global__ __launch_bounds__(256) void gate_outproj_ln(
    const float* __restrict__ r_mean, const float* __restrict__ r_max, const float* __restrict__ r_sum,
    const float* __restrict__ gwm, const float* __restrict__ gbm,
    const float* __restrict__ gwx, const float* __restrict__ gbx,
    const float* __restrict__ gws, const float* __restrict__ gbs,
    const float* __restrict__ Wout, const float* __restrict__ bout,
    const float* __restrict__ gamma, const float* __restrict__ beta,
    float* __restrict__ out)
{
    int g0 = blockIdx.x * EM;
    int tid = threadIdx.x;
    __shared__ float Rm[EM][HID], Rx[EM][HID], Rs[EM][HID];  // 24 KB
    __shared__ float Ps[EM][HID];                            // 8 KB
    __shared__ float Es[EM][IN_F];                           // 4 KB
    __shared__ float wgt[EM][3];

    const float4* rm4 = (const float4*)(r_mean + (size_t)g0*HID);
    const float4* rx4 = (const float4*)(r_max  + (size_t)g0*HID);
    const float4* rs4 = (const float4*)(r_sum  + (size_t)g0*HID);
    #pragma unroll
    for (int i = 0; i < 2; ++i) {
        int idx = tid + i*256;       // 0..511 float4s = 4 graphs x 512 floats
        ((float4*)Rm)[idx] = rm4[idx];
        ((float4*)Rx)[idx] = rx4[idx];
        ((float4*)Rs)[idx] = rs4[idx];
    }
    __syncthreads();

    // gates: wave w -> graph w
    int w = tid >> 6, lane = tid & 63;
    float dm = 0.f, dx = 0.f, dsv = 0.f;
    #pragma unroll
    for (int j = 0; j < 8; ++j) {
        int k = lane + j*64;
        dm  += Rm[w][k] * gwm[k];
        dx  += Rx[w][k] * gwx[k];
        dsv += Rs[w][k] * gws[k];
    }
    #pragma unroll
    for (int off = 32; off > 0; off >>= 1) {
        dm  += __shfl_xor(dm,  off, 64);
        dx  += __shfl_xor(dx,  off, 64);
        dsv += __shfl_xor(dsv, off, 64);
    }
    if (lane == 0) {
        float sm = 1.f/(1.f + expf(-(dm  + gbm[0])));
        float sx = 1.f/(1.f + expf(-(dx  + gbx[0])));
        float ss = 1.f/(1.f + expf(-(dsv + gbs[0])));
        float em = expf(sm), ex = expf(sx), es = expf(ss);
        float inv = 1.f/(em + ex + es);
        wgt[w][0] = em*inv; wgt[w][1] = ex*inv; wgt[w][2] = es*inv;
    }
    __syncthreads();

    // pooled = w0*mean_repr + w1*max_repr + w2*sum_repr
    #pragma unroll
    for (int i = 0; i < 8; ++i) {
        int e = tid + i*256;          // 0..2047
        int j = e >> 9, k = e & 511;
        Ps[j][k] = wgt[j][0]*Rm[j][k] + wgt[j][1]*Rx[j][k] + wgt[j][2]*Rs[j][k];
    }
    __syncthreads();

    // out-projection: thread = output feature f, 4 graph rows at once
    float a0 = 0.f, a1 = 0.f, a2 = 0.f, a3 = 0.f;
    int f = tid;
    for (int k = 0; k < HID; k += 4) {
        float4 p0 = *(const float4*)&Ps[0][k];   // broadcast b128 reads
        float4 p1 = *(const float4*)&Ps[1][k];
        float4 p2 = *(const float4*)&Ps[2][k];
        float4 p3 = *(const float4*)&Ps[3][k];
        float w0 = Wout[(size_t)(k+0)*IN_F + f]; // coalesced 1KB/block-row
        float w1 = Wout[(size_t)(k+1)*IN_F + f];
        float w2 = Wout[(size_t)(k+2)*IN_F + f];
        float w3 = Wout[(size_t)(k+3)*IN_F + f];
        a0 += p0.x*w0 + p0.y*w1 + p0.z*w2 + p0.w*w3;
        a1 += p1.x*w0 + p1.y*w1 + p1.z*w2 + p1.w*w3;
        a2 += p2.x*w0 + p2.y*w1 + p2.z*w2 + p2.w*w3;
        a3 += p3.x*w0 + p3.y*w1 + p3.z*w2 + p3.w*w3;
    }
    float bo = bout[f];
    Es[0][f] = a0 + bo; Es[1][f] = a1 + bo; Es[2][f] = a2 + bo; Es[3][f] = a3 + bo;
    __syncthreads();

    // layernorm: wave w normalizes row w (256 feats, 4/lane)
    float v0 = Es[w][lane], v1 = Es[w][lane+64], v2 = Es[w][lane+128], v3 = Es[w][lane+192];
    float s  = (v0+v1) + (v2+v3);
    float sq = (v0*v0 + v1*v1) + (v2*v2 + v3*v3);
    #pragma unroll
    for (int off = 32; off > 0; off >>= 1) {
        s  += __shfl_xor(s,  off, 64);
        sq += __shfl_xor(sq, off, 64);
    }
    float mu  = s * (1.0f/IN_F);
    float var = sq * (1.0f/IN_F) - mu*mu;
    float rs  = rsqrtf(var + 1e-5f);
    float* orow = out + (size_t)(g0 + w)*IN_F;
    orow[lane]     = (v0-mu)*rs*gamma[lane]     + beta[lane];
    orow[lane+64]  = (v1-mu)*rs*gamma[lane+64]  + beta[lane+64];
    orow[lane+128] = (v2-mu)*rs*gamma[lane+128] + beta[lane+128];
    orow[lane+192] = (v3-mu)*rs*gamma[lane+192] + beta[lane+192];
}

extern "C" void kernel_launch(void* const* d_in, const int* in_sizes, int n_in,
                              void* d_out, int out_size, void* d_ws, size_t ws_size,
                              hipStream_t stream)
{
    const float* x        = (const float*)d_in[0];
    const int*   batch    = (const int*)d_in[1];
    const float* W_mean   = (const float*)d_in[2];
    const float* b_mean   = (const float*)d_in[3];
    const float* W_max    = (const float*)d_in[4];
    const float* b_max    = (const float*)d_in[5];
    const float* W_sum    = (const float*)d_in[6];
    const float* b_sum    = (const float*)d_in[7];
    const float* g_mean_w = (const float*)d_in[8];
    const float* g_mean_b = (const float*)d_in[9];
    const float* g_max_w  = (const float*)d_in[10];
    const float* g_max_b  = (const float*)d_in[11];
    const float* g_sum_w  = (const float*)d_in[12];
    const float* g_sum_b  = (const float*)d_in[13];
    const float* W_out    = (const float*)d_in[14];
    const float* b_out    = (const float*)d_in[15];
    const float* ln_gamma = (const float*)d_in[16];
    const float* ln_beta  = (const float*)d_in[17];
    float* out = (float*)d_out;
    int N = in_sizes[1];   // 200000 nodes

    // workspace (floats): 3 pools [1024,256], 3 reprs [1024,512]
    float* ws        = (float*)d_ws;
    float* sum_pool  = ws;
    float* mean_pool = ws + (size_t)NUM_GRAPHS*IN_F;
    float* max_pool  = ws + (size_t)2*NUM_GRAPHS*IN_F;
    float* r_mean    = ws + (size_t)3*NUM_GRAPHS*IN_F;
    float* r_max     = r_mean + (size_t)NUM_GRAPHS*HID;
    float* r_sum     = r_max  + (size_t)NUM_GRAPHS*HID;

    pool_kernel<<<NUM_GRAPHS, 256, 0, stream>>>(x, batch, N, sum_pool, mean_pool, max_pool);

    dim3 gridC(HID/BN, NUM_GRAPHS/BM, 3);   // (8,16,3) = 384 blocks
    transform_gemm<<<gridC, 256, 0, stream>>>(mean_pool, max_pool, sum_pool,
                                              W_mean, b_mean, W_max, b_max, W_sum, b_sum,
                                              r_mean, r_max, r_sum);

    gate_outproj_ln<<<NUM_GRAPHS/EM, 256, 0, stream>>>(r_mean, r_max, r_sum,
                                                       g_mean_w, g_mean_b, g_max_w, g_max_b,
                                                       g_sum_w, g_sum_b,
                                                       W_out, b_out, ln_gamma, ln_beta, out);
}

// Round 3
// 394.277 us; speedup vs baseline: 1.0382x; 1.0260x over previous
//
#include <hip/hip_runtime.h>
#include <math.h>

#define NUM_GRAPHS 1024
#define IN_F 256
#define HID 512

typedef __bf16 bf16x4 __attribute__((ext_vector_type(4)));
typedef __bf16 bf16x8 __attribute__((ext_vector_type(8)));
typedef float  f32x4  __attribute__((ext_vector_type(4)));

// ---------------- K0: prep = W transpose->bf16 (blocks 0..95) + segment bounds ----------------
// Wt_z[n][k] = (bf16)W_z[k][n]; seg_start[g] = lower_bound(batch, g), seg_start[1024]=N.
__global__ __launch_bounds__(256) void prep_kernel(
    const float* __restrict__ Wm, const float* __restrict__ Wx, const float* __restrict__ Wsm,
    __bf16* __restrict__ wt,            // 3 x [HID][IN_F]
    const int* __restrict__ batch, int N, int* __restrict__ seg)
{
    int b = blockIdx.x;
    if (b < 96) {                       // 3 z * (256/64 kt) * (512/64 nt)
        __shared__ float tile[64][65];
        int z  = b / 32;
        int kt = (b % 32) / 8, nt = b % 8;
        const float* W = (z==0) ? Wm : (z==1) ? Wx : Wsm;
        __bf16* Wt = wt + (size_t)z * HID * IN_F;
        int k0 = kt * 64, n0 = nt * 64;
        int r  = threadIdx.x >> 2;          // 0..63
        int c0 = (threadIdx.x & 3) * 16;    // 0,16,32,48
        #pragma unroll
        for (int j = 0; j < 4; ++j) {
            float4 v = *(const float4*)&W[(size_t)(k0 + r)*HID + n0 + c0 + j*4];
            tile[r][c0+j*4+0] = v.x; tile[r][c0+j*4+1] = v.y;
            tile[r][c0+j*4+2] = v.z; tile[r][c0+j*4+3] = v.w;
        }
        __syncthreads();
        #pragma unroll
        for (int j = 0; j < 4; ++j) {
            bf16x4 o;
            o.x = (__bf16)tile[c0+j*4+0][r];
            o.y = (__bf16)tile[c0+j*4+1][r];
            o.z = (__bf16)tile[c0+j*4+2][r];
            o.w = (__bf16)tile[c0+j*4+3][r];
            *(bf16x4*)&Wt[(size_t)(n0 + r)*IN_F + k0 + c0 + j*4] = o;
        }
    } else {                            // boundary kernel: adjacent-difference on sorted batch
        int i = (b - 96) * 256 + threadIdx.x;
        if (i <= N) {
            int cur  = (i < N) ? batch[i] : NUM_GRAPHS;
            int prev = (i == 0) ? -1 : batch[i-1];
            for (int g = prev + 1; g <= cur; ++g) seg[g] = i;
        }
    }
}

// ---------------- K1: segment sum/mean/max pooling -> bf16 pools ----------------
__global__ __launch_bounds__(256) void pool_kernel(
    const float* __restrict__ x, const int* __restrict__ seg,
    __bf16* __restrict__ pool_mean, __bf16* __restrict__ pool_max,
    __bf16* __restrict__ pool_sum)
{
    int g = blockIdx.x;
    int start = seg[g], end = seg[g+1];
    int cnt = end - start;
    int w = threadIdx.x >> 6, lane = threadIdx.x & 63;
    const float4* x4 = (const float4*)x;     // row r at x4[r*64 + lane]
    float4 s = make_float4(0.f, 0.f, 0.f, 0.f);
    float4 m = make_float4(-INFINITY, -INFINITY, -INFINITY, -INFINITY);
    int r = start + w;
    for (; r + 12 < end; r += 16) {
        float4 v0 = x4[(size_t)(r     )*64 + lane];
        float4 v1 = x4[(size_t)(r +  4)*64 + lane];
        float4 v2 = x4[(size_t)(r +  8)*64 + lane];
        float4 v3 = x4[(size_t)(r + 12)*64 + lane];
        s.x += (v0.x+v1.x)+(v2.x+v3.x); s.y += (v0.y+v1.y)+(v2.y+v3.y);
        s.z += (v0.z+v1.z)+(v2.z+v3.z); s.w += (v0.w+v1.w)+(v2.w+v3.w);
        m.x = fmaxf(m.x, fmaxf(fmaxf(v0.x,v1.x), fmaxf(v2.x,v3.x)));
        m.y = fmaxf(m.y, fmaxf(fmaxf(v0.y,v1.y), fmaxf(v2.y,v3.y)));
        m.z = fmaxf(m.z, fmaxf(fmaxf(v0.z,v1.z), fmaxf(v2.z,v3.z)));
        m.w = fmaxf(m.w, fmaxf(fmaxf(v0.w,v1.w), fmaxf(v2.w,v3.w)));
    }
    for (; r < end; r += 4) {
        float4 v = x4[(size_t)r*64 + lane];
        s.x += v.x; s.y += v.y; s.z += v.z; s.w += v.w;
        m.x = fmaxf(m.x, v.x); m.y = fmaxf(m.y, v.y);
        m.z = fmaxf(m.z, v.z); m.w = fmaxf(m.w, v.w);
    }
    __shared__ float4 Ls[4][64];
    __shared__ float4 Lm[4][64];
    Ls[w][lane] = s; Lm[w][lane] = m;
    __syncthreads();
    if (w == 0) {
        float4 s0 = Ls[0][lane], s1 = Ls[1][lane], s2 = Ls[2][lane], s3 = Ls[3][lane];
        float4 m0 = Lm[0][lane], m1 = Lm[1][lane], m2 = Lm[2][lane], m3 = Lm[3][lane];
        float4 st, mt;
        st.x = (s0.x+s1.x)+(s2.x+s3.x); st.y = (s0.y+s1.y)+(s2.y+s3.y);
        st.z = (s0.z+s1.z)+(s2.z+s3.z); st.w = (s0.w+s1.w)+(s2.w+s3.w);
        mt.x = fmaxf(fmaxf(m0.x,m1.x), fmaxf(m2.x,m3.x));
        mt.y = fmaxf(fmaxf(m0.y,m1.y), fmaxf(m2.y,m3.y));
        mt.z = fmaxf(fmaxf(m0.z,m1.z), fmaxf(m2.z,m3.z));
        mt.w = fmaxf(fmaxf(m0.w,m1.w), fmaxf(m2.w,m3.w));
        float inv = 1.0f / fmaxf((float)cnt, 1.0f);
        if (cnt == 0) mt = make_float4(0.f, 0.f, 0.f, 0.f);
        bf16x4 sb, mb, xb;
        sb.x = (__bf16)st.x;       sb.y = (__bf16)st.y;
        sb.z = (__bf16)st.z;       sb.w = (__bf16)st.w;
        mb.x = (__bf16)(st.x*inv); mb.y = (__bf16)(st.y*inv);
        mb.z = (__bf16)(st.z*inv); mb.w = (__bf16)(st.w*inv);
        xb.x = (__bf16)mt.x;       xb.y = (__bf16)mt.y;
        xb.z = (__bf16)mt.z;       xb.w = (__bf16)mt.w;
        size_t o = (size_t)g*64 + lane;
        ((bf16x4*)pool_sum)[o]  = sb;
        ((bf16x4*)pool_mean)[o] = mb;
        ((bf16x4*)pool_max)[o]  = xb;
    }
}

// ---------------- K2: three transform GEMMs via bf16 MFMA, zero LDS ----------------
// repr_z = pool_z @ W_z + b_z. A=[1024,256]bf16 row-major, Bt=[512,256]bf16 (W^T).
// Block = 64x64 tile, wave w = rows w*16..w*16+15 x 64 cols (4 MFMA 16x16x32 tiles).
// Fragments loaded directly from global (L2/L3-resident, ~2.25 MB unique).
__global__ __launch_bounds__(256) void transform_mfma(
    const __bf16* __restrict__ pm, const __bf16* __restrict__ px, const __bf16* __restrict__ ps,
    const __bf16* __restrict__ wtm, const __bf16* __restrict__ wtx, const __bf16* __restrict__ wts,
    const float* __restrict__ bm_, const float* __restrict__ bx_, const float* __restrict__ bs_,
    float* __restrict__ r_mean, float* __restrict__ r_max, float* __restrict__ r_sum)
{
    int z = blockIdx.z;
    const __bf16* A  = (z==0) ? pm  : (z==1) ? px  : ps;
    const __bf16* Bt = (z==0) ? wtm : (z==1) ? wtx : wts;
    const float* bias= (z==0) ? bm_ : (z==1) ? bx_ : bs_;
    float* R         = (z==0) ? r_mean : (z==1) ? r_max : r_sum;

    int bn0 = blockIdx.x * 64;
    int bm0 = blockIdx.y * 64;
    int w = threadIdx.x >> 6, lane = threadIdx.x & 63;
    int qm = lane >> 4, rm = lane & 15;
    // A-frag: lane holds A[m = rm][k = qm*8 .. +7]; frag j at element (j*4 + qm) of bf16x8 row
    const bf16x8* Arow = (const bf16x8*)(A + (size_t)(bm0 + w*16 + rm)*IN_F);
    // B-frag: lane holds B[k = qm*8..][n = rm] = Wt[n][k..] (k-contiguous thanks to transpose)
    const bf16x8* B0 = (const bf16x8*)(Bt + (size_t)(bn0 +  0 + rm)*IN_F);
    const bf16x8* B1 = (const bf16x8*)(Bt + (size_t)(bn0 + 16 + rm)*IN_F);
    const bf16x8* B2 = (const bf16x8*)(Bt + (size_t)(bn0 + 32 + rm)*IN_F);
    const bf16x8* B3 = (const bf16x8*)(Bt + (size_t)(bn0 + 48 + rm)*IN_F);
    f32x4 a0 = {0.f,0.f,0.f,0.f}, a1 = a0, a2 = a0, a3 = a0;
    #pragma unroll
    for (int j = 0; j < 8; ++j) {        // K = 256 in chunks of 32
        int fi = j*4 + qm;
        bf16x8 af = Arow[fi];
        a0 = __builtin_amdgcn_mfma_f32_16x16x32_bf16(af, B0[fi], a0, 0, 0, 0);
        a1 = __builtin_amdgcn_mfma_f32_16x16x32_bf16(af, B1[fi], a1, 0, 0, 0);
        a2 = __builtin_amdgcn_mfma_f32_16x16x32_bf16(af, B2[fi], a2, 0, 0, 0);
        a3 = __builtin_amdgcn_mfma_f32_16x16x32_bf16(af, B3[fi], a3, 0, 0, 0);
    }
    // C/D layout: col = lane&15, row = (lane>>4)*4 + reg  [guide §3, m89-verified]
    int row0 = bm0 + w*16 + qm*4;
    float b0 = bias[bn0 +  0 + rm], b1 = bias[bn0 + 16 + rm];
    float b2 = bias[bn0 + 32 + rm], b3 = bias[bn0 + 48 + rm];
    #pragma unroll
    for (int r = 0; r < 4; ++r) {
        float* Rr = R + (size_t)(row0 + r)*HID;
        Rr[bn0 +  0 + rm] = a0[r] + b0;
        Rr[bn0 + 16 + rm] = a1[r] + b1;
        Rr[bn0 + 32 + rm] = a2[r] + b2;
        Rr[bn0 + 48 + rm] = a3[r] + b3;
    }
}

// ---------------- K3: gates + fusion + output projection + layernorm ----------------
#define EM 4
__global__ __launch_bounds__(256) void gate_outproj_ln(
    const float* __restrict__ r_mean, const float* __restrict__ r_max, const float* __restrict__ r_sum,
    const float* __restrict__ gwm, const float* __restrict__ gbm,
    const float* __restrict__ gwx, const float* __restrict__ gbx,
    const float* __restrict__ gws, const float* __restrict__ gbs,
    const float* __restrict__ Wout, const float* __restrict__ bout,
    const float* __restrict__ gamma, const float* __restrict__ beta,
    float* __restrict__ out)
{
    int g0 = blockIdx.x * EM;
    int tid = threadIdx.x;
    __shared__ float Rm[EM][HID], Rx[EM][HID], Rs[EM][HID];  // 24 KB
    __shared__ float Ps[EM][HID];                            // 8 KB
    __shared__ float Es[EM][IN_F];                           // 4 KB
    __shared__ float wgt[EM][3];

    const float4* rm4 = (const float4*)(r_mean + (size_t)g0*HID);
    const float4* rx4 = (const float4*)(r_max  + (size_t)g0*HID);
    const float4* rs4 = (const float4*)(r_sum  + (size_t)g0*HID);
    #pragma unroll
    for (int i = 0; i < 2; ++i) {
        int idx = tid + i*256;
        ((float4*)Rm)[idx] = rm4[idx];
        ((float4*)Rx)[idx] = rx4[idx];
        ((float4*)Rs)[idx] = rs4[idx];
    }
    __syncthreads();

    int w = tid >> 6, lane = tid & 63;
    float dm = 0.f, dx = 0.f, dsv = 0.f;
    #pragma unroll
    for (int j = 0; j < 8; ++j) {
        int k = lane + j*64;
        dm  += Rm[w][k] * gwm[k];
        dx  += Rx[w][k] * gwx[k];
        dsv += Rs[w][k] * gws[k];
    }
    #pragma unroll
    for (int off = 32; off > 0; off >>= 1) {
        dm  += __shfl_xor(dm,  off, 64);
        dx  += __shfl_xor(dx,  off, 64);
        dsv += __shfl_xor(dsv, off, 64);
    }
    if (lane == 0) {
        float sm = 1.f/(1.f + expf(-(dm  + gbm[0])));
        float sx = 1.f/(1.f + expf(-(dx  + gbx[0])));
        float ss = 1.f/(1.f + expf(-(dsv + gbs[0])));
        float em = expf(sm), ex = expf(sx), es = expf(ss);
        float inv = 1.f/(em + ex + es);
        wgt[w][0] = em*inv; wgt[w][1] = ex*inv; wgt[w][2] = es*inv;
    }
    __syncthreads();

    #pragma unroll
    for (int i = 0; i < 8; ++i) {
        int e = tid + i*256;
        int j = e >> 9, k = e & 511;
        Ps[j][k] = wgt[j][0]*Rm[j][k] + wgt[j][1]*Rx[j][k] + wgt[j][2]*Rs[j][k];
    }
    __syncthreads();

    float a0 = 0.f, a1 = 0.f, a2 = 0.f, a3 = 0.f;
    int f = tid;
    for (int k = 0; k < HID; k += 4) {
        float4 p0 = *(const float4*)&Ps[0][k];
        float4 p1 = *(const float4*)&Ps[1][k];
        float4 p2 = *(const float4*)&Ps[2][k];
        float4 p3 = *(const float4*)&Ps[3][k];
        float w0 = Wout[(size_t)(k+0)*IN_F + f];
        float w1 = Wout[(size_t)(k+1)*IN_F + f];
        float w2 = Wout[(size_t)(k+2)*IN_F + f];
        float w3 = Wout[(size_t)(k+3)*IN_F + f];
        a0 += p0.x*w0 + p0.y*w1 + p0.z*w2 + p0.w*w3;
        a1 += p1.x*w0 + p1.y*w1 + p1.z*w2 + p1.w*w3;
        a2 += p2.x*w0 + p2.y*w1 + p2.z*w2 + p2.w*w3;
        a3 += p3.x*w0 + p3.y*w1 + p3.z*w2 + p3.w*w3;
    }
    float bo = bout[f];
    Es[0][f] = a0 + bo; Es[1][f] = a1 + bo; Es[2][f] = a2 + bo; Es[3][f] = a3 + bo;
    __syncthreads();

    float v0 = Es[w][lane], v1 = Es[w][lane+64], v2 = Es[w][lane+128], v3 = Es[w][lane+192];
    float s  = (v0+v1) + (v2+v3);
    float sq = (v0*v0 + v1*v1) + (v2*v2 + v3*v3);
    #pragma unroll
    for (int off = 32; off > 0; off >>= 1) {
        s  += __shfl_xor(s,  off, 64);
        sq += __shfl_xor(sq, off, 64);
    }
    float mu  = s * (1.0f/IN_F);
    float var = sq * (1.0f/IN_F) - mu*mu;
    float rs  = rsqrtf(var + 1e-5f);
    float* orow = out + (size_t)(g0 + w)*IN_F;
    orow[lane]     = (v0-mu)*rs*gamma[lane]     + beta[lane];
    orow[lane+64]  = (v1-mu)*rs*gamma[lane+64]  + beta[lane+64];
    orow[lane+128] = (v2-mu)*rs*gamma[lane+128] + beta[lane+128];
    orow[lane+192] = (v3-mu)*rs*gamma[lane+192] + beta[lane+192];
}

extern "C" void kernel_launch(void* const* d_in, const int* in_sizes, int n_in,
                              void* d_out, int out_size, void* d_ws, size_t ws_size,
                              hipStream_t stream)
{
    const float* x        = (const float*)d_in[0];
    const int*   batch    = (const int*)d_in[1];
    const float* W_mean   = (const float*)d_in[2];
    const float* b_mean   = (const float*)d_in[3];
    const float* W_max    = (const float*)d_in[4];
    const float* b_max    = (const float*)d_in[5];
    const float* W_sum    = (const float*)d_in[6];
    const float* b_sum    = (const float*)d_in[7];
    const float* g_mean_w = (const float*)d_in[8];
    const float* g_mean_b = (const float*)d_in[9];
    const float* g_max_w  = (const float*)d_in[10];
    const float* g_max_b  = (const float*)d_in[11];
    const float* g_sum_w  = (const float*)d_in[12];
    const float* g_sum_b  = (const float*)d_in[13];
    const float* W_out    = (const float*)d_in[14];
    const float* b_out    = (const float*)d_in[15];
    const float* ln_gamma = (const float*)d_in[16];
    const float* ln_beta  = (const float*)d_in[17];
    float* out = (float*)d_out;
    int N = in_sizes[1];   // 200000 nodes

    // workspace layout
    float* ws      = (float*)d_ws;
    float* r_mean  = ws;                                  // [1024,512] f32
    float* r_max   = r_mean + (size_t)NUM_GRAPHS*HID;
    float* r_sum   = r_max  + (size_t)NUM_GRAPHS*HID;
    __bf16* pool_bf = (__bf16*)(r_sum + (size_t)NUM_GRAPHS*HID);
    __bf16* pm  = pool_bf;                                // [1024,256] bf16 x3
    __bf16* px  = pm + (size_t)NUM_GRAPHS*IN_F;
    __bf16* psu = px + (size_t)NUM_GRAPHS*IN_F;
    __bf16* wt  = psu + (size_t)NUM_GRAPHS*IN_F;          // [512,256] bf16 x3
    __bf16* wtm = wt;
    __bf16* wtx = wtm + (size_t)HID*IN_F;
    __bf16* wts = wtx + (size_t)HID*IN_F;
    int* seg    = (int*)(wts + (size_t)HID*IN_F);         // [1025]

    int bnd_blocks = (N + 1 + 255) / 256;
    prep_kernel<<<96 + bnd_blocks, 256, 0, stream>>>(W_mean, W_max, W_sum, wt, batch, N, seg);

    pool_kernel<<<NUM_GRAPHS, 256, 0, stream>>>(x, seg, pm, px, psu);

    dim3 gridC(HID/64, NUM_GRAPHS/64, 3);   // (8,16,3) = 384 blocks
    transform_mfma<<<gridC, 256, 0, stream>>>(pm, px, psu, wtm, wtx, wts,
                                              b_mean, b_max, b_sum,
                                              r_mean, r_max, r_sum);

    gate_outproj_ln<<<NUM_GRAPHS/EM, 256, 0, stream>>>(r_mean, r_max, r_sum,
                                                       g_mean_w, g_mean_b, g_max_w, g_max_b,
                                                       g_sum_w, g_sum_b,
                                                       W_out, b_out, ln_gamma, ln_beta, out);
}

// Round 4
// 344.981 us; speedup vs baseline: 1.1865x; 1.1429x over previous
//
#include <hip/hip_runtime.h>
#include <math.h>

#define NUM_GRAPHS 1024
#define IN_F 256
#define HID 512

typedef __bf16 bf16x4 __attribute__((ext_vector_type(4)));
typedef __bf16 bf16x8 __attribute__((ext_vector_type(8)));
typedef float  f32x4  __attribute__((ext_vector_type(4)));

__device__ __forceinline__ int lower_bound_i(const int* __restrict__ b, int n, int v) {
    int lo = 0, hi = n;
    while (lo < hi) {
        int mid = (lo + hi) >> 1;
        if (b[mid] < v) lo = mid + 1; else hi = mid;
    }
    return lo;
}

__device__ __forceinline__ float bdot8(bf16x8 a, float4 w0, float4 w1) {
    return (float)a[0]*w0.x + (float)a[1]*w0.y + (float)a[2]*w0.z + (float)a[3]*w0.w
         + (float)a[4]*w1.x + (float)a[5]*w1.y + (float)a[6]*w1.z + (float)a[7]*w1.w;
}

// ---------------- L1: pooling (blocks 0..1023) + W transposes (blocks 1024..1151) ----------------
// Pool: one block/graph, inline binary search on sorted batch, float4 row reads,
// cross-wave LDS combine, bf16 pool outputs.
// Transpose: 64x64 f32 tiles -> bf16, dst[n][k] = src[k][n]; z=0..2 transform W's
// ([256,512]->[512,256]), z=3 W_out ([512,256]->[256,512]).
__global__ __launch_bounds__(256) void pool_prep_kernel(
    const float* __restrict__ x, const int* __restrict__ batch, int N,
    __bf16* __restrict__ pool_mean, __bf16* __restrict__ pool_max,
    __bf16* __restrict__ pool_sum,
    const float* __restrict__ Wm, const float* __restrict__ Wx, const float* __restrict__ Wsm,
    const float* __restrict__ Wout,
    __bf16* __restrict__ wt,      // 3 x [512][256]
    __bf16* __restrict__ wtout)   // [256][512]
{
    if (blockIdx.x >= NUM_GRAPHS) {
        // ---- transpose role ----
        __shared__ float tile[64][65];
        int tb = blockIdx.x - NUM_GRAPHS;     // 0..127
        int z = tb >> 5, t = tb & 31;
        const float* S; __bf16* D; int SC, SR, r0, cb;
        if (z < 3) {
            S = (z==0) ? Wm : (z==1) ? Wx : Wsm;
            D = wt + (size_t)z * HID * IN_F;
            SR = 256; SC = 512;
            r0 = (t >> 3) * 64; cb = (t & 7) * 64;
        } else {
            S = Wout; D = wtout;
            SR = 512; SC = 256;
            r0 = (t >> 2) * 64; cb = (t & 3) * 64;
        }
        int r  = threadIdx.x >> 2;
        int c0 = (threadIdx.x & 3) * 16;
        #pragma unroll
        for (int j = 0; j < 4; ++j) {
            float4 v = *(const float4*)&S[(size_t)(r0 + r)*SC + cb + c0 + j*4];
            tile[r][c0+j*4+0] = v.x; tile[r][c0+j*4+1] = v.y;
            tile[r][c0+j*4+2] = v.z; tile[r][c0+j*4+3] = v.w;
        }
        __syncthreads();
        #pragma unroll
        for (int j = 0; j < 4; ++j) {
            bf16x4 o;
            o.x = (__bf16)tile[c0+j*4+0][r];
            o.y = (__bf16)tile[c0+j*4+1][r];
            o.z = (__bf16)tile[c0+j*4+2][r];
            o.w = (__bf16)tile[c0+j*4+3][r];
            *(bf16x4*)&D[(size_t)(cb + r)*SR + r0 + c0 + j*4] = o;
        }
        return;
    }
    // ---- pool role ----
    int g = blockIdx.x;
    __shared__ int sb[2];
    if (threadIdx.x < 2) sb[threadIdx.x] = lower_bound_i(batch, N, g + (int)threadIdx.x);
    __syncthreads();
    int start = sb[0], end = sb[1];
    int cnt = end - start;
    int w = threadIdx.x >> 6, lane = threadIdx.x & 63;
    const float4* x4 = (const float4*)x;
    float4 s = make_float4(0.f, 0.f, 0.f, 0.f);
    float4 m = make_float4(-INFINITY, -INFINITY, -INFINITY, -INFINITY);
    int r = start + w;
    for (; r + 12 < end; r += 16) {
        float4 v0 = x4[(size_t)(r     )*64 + lane];
        float4 v1 = x4[(size_t)(r +  4)*64 + lane];
        float4 v2 = x4[(size_t)(r +  8)*64 + lane];
        float4 v3 = x4[(size_t)(r + 12)*64 + lane];
        s.x += (v0.x+v1.x)+(v2.x+v3.x); s.y += (v0.y+v1.y)+(v2.y+v3.y);
        s.z += (v0.z+v1.z)+(v2.z+v3.z); s.w += (v0.w+v1.w)+(v2.w+v3.w);
        m.x = fmaxf(m.x, fmaxf(fmaxf(v0.x,v1.x), fmaxf(v2.x,v3.x)));
        m.y = fmaxf(m.y, fmaxf(fmaxf(v0.y,v1.y), fmaxf(v2.y,v3.y)));
        m.z = fmaxf(m.z, fmaxf(fmaxf(v0.z,v1.z), fmaxf(v2.z,v3.z)));
        m.w = fmaxf(m.w, fmaxf(fmaxf(v0.w,v1.w), fmaxf(v2.w,v3.w)));
    }
    for (; r < end; r += 4) {
        float4 v = x4[(size_t)r*64 + lane];
        s.x += v.x; s.y += v.y; s.z += v.z; s.w += v.w;
        m.x = fmaxf(m.x, v.x); m.y = fmaxf(m.y, v.y);
        m.z = fmaxf(m.z, v.z); m.w = fmaxf(m.w, v.w);
    }
    __shared__ float4 Ls[4][64];
    __shared__ float4 Lm[4][64];
    Ls[w][lane] = s; Lm[w][lane] = m;
    __syncthreads();
    if (w == 0) {
        float4 s0 = Ls[0][lane], s1 = Ls[1][lane], s2 = Ls[2][lane], s3 = Ls[3][lane];
        float4 m0 = Lm[0][lane], m1 = Lm[1][lane], m2 = Lm[2][lane], m3 = Lm[3][lane];
        float4 st, mt;
        st.x = (s0.x+s1.x)+(s2.x+s3.x); st.y = (s0.y+s1.y)+(s2.y+s3.y);
        st.z = (s0.z+s1.z)+(s2.z+s3.z); st.w = (s0.w+s1.w)+(s2.w+s3.w);
        mt.x = fmaxf(fmaxf(m0.x,m1.x), fmaxf(m2.x,m3.x));
        mt.y = fmaxf(fmaxf(m0.y,m1.y), fmaxf(m2.y,m3.y));
        mt.z = fmaxf(fmaxf(m0.z,m1.z), fmaxf(m2.z,m3.z));
        mt.w = fmaxf(fmaxf(m0.w,m1.w), fmaxf(m2.w,m3.w));
        float inv = 1.0f / fmaxf((float)cnt, 1.0f);
        if (cnt == 0) mt = make_float4(0.f, 0.f, 0.f, 0.f);
        bf16x4 sb4, mb4, xb4;
        sb4.x = (__bf16)st.x;       sb4.y = (__bf16)st.y;
        sb4.z = (__bf16)st.z;       sb4.w = (__bf16)st.w;
        mb4.x = (__bf16)(st.x*inv); mb4.y = (__bf16)(st.y*inv);
        mb4.z = (__bf16)(st.z*inv); mb4.w = (__bf16)(st.w*inv);
        xb4.x = (__bf16)mt.x;       xb4.y = (__bf16)mt.y;
        xb4.z = (__bf16)mt.z;       xb4.w = (__bf16)mt.w;
        size_t o = (size_t)g*64 + lane;
        ((bf16x4*)pool_sum)[o]  = sb4;
        ((bf16x4*)pool_mean)[o] = mb4;
        ((bf16x4*)pool_max)[o]  = xb4;
    }
}

// ---------------- L2: three transform GEMMs via bf16 MFMA, zero LDS, bf16 out ----------------
__global__ __launch_bounds__(256) void transform_mfma(
    const __bf16* __restrict__ pm, const __bf16* __restrict__ px, const __bf16* __restrict__ ps,
    const __bf16* __restrict__ wtm, const __bf16* __restrict__ wtx, const __bf16* __restrict__ wts,
    const float* __restrict__ bm_, const float* __restrict__ bx_, const float* __restrict__ bs_,
    __bf16* __restrict__ r_mean, __bf16* __restrict__ r_max, __bf16* __restrict__ r_sum)
{
    int z = blockIdx.z;
    const __bf16* A  = (z==0) ? pm  : (z==1) ? px  : ps;
    const __bf16* Bt = (z==0) ? wtm : (z==1) ? wtx : wts;
    const float* bias= (z==0) ? bm_ : (z==1) ? bx_ : bs_;
    __bf16* R        = (z==0) ? r_mean : (z==1) ? r_max : r_sum;

    int bn0 = blockIdx.x * 64;
    int bm0 = blockIdx.y * 64;
    int w = threadIdx.x >> 6, lane = threadIdx.x & 63;
    int qm = lane >> 4, rm = lane & 15;
    const bf16x8* Arow = (const bf16x8*)(A + (size_t)(bm0 + w*16 + rm)*IN_F);
    const bf16x8* B0 = (const bf16x8*)(Bt + (size_t)(bn0 +  0 + rm)*IN_F);
    const bf16x8* B1 = (const bf16x8*)(Bt + (size_t)(bn0 + 16 + rm)*IN_F);
    const bf16x8* B2 = (const bf16x8*)(Bt + (size_t)(bn0 + 32 + rm)*IN_F);
    const bf16x8* B3 = (const bf16x8*)(Bt + (size_t)(bn0 + 48 + rm)*IN_F);
    f32x4 a0 = {0.f,0.f,0.f,0.f}, a1 = a0, a2 = a0, a3 = a0;
    #pragma unroll
    for (int j = 0; j < 8; ++j) {
        int fi = j*4 + qm;
        bf16x8 af = Arow[fi];
        a0 = __builtin_amdgcn_mfma_f32_16x16x32_bf16(af, B0[fi], a0, 0, 0, 0);
        a1 = __builtin_amdgcn_mfma_f32_16x16x32_bf16(af, B1[fi], a1, 0, 0, 0);
        a2 = __builtin_amdgcn_mfma_f32_16x16x32_bf16(af, B2[fi], a2, 0, 0, 0);
        a3 = __builtin_amdgcn_mfma_f32_16x16x32_bf16(af, B3[fi], a3, 0, 0, 0);
    }
    int row0 = bm0 + w*16 + qm*4;
    float b0 = bias[bn0 +  0 + rm], b1 = bias[bn0 + 16 + rm];
    float b2 = bias[bn0 + 32 + rm], b3 = bias[bn0 + 48 + rm];
    #pragma unroll
    for (int r = 0; r < 4; ++r) {
        __bf16* Rr = R + (size_t)(row0 + r)*HID;
        Rr[bn0 +  0 + rm] = (__bf16)(a0[r] + b0);
        Rr[bn0 + 16 + rm] = (__bf16)(a1[r] + b1);
        Rr[bn0 + 32 + rm] = (__bf16)(a2[r] + b2);
        Rr[bn0 + 48 + rm] = (__bf16)(a3[r] + b3);
    }
}

// ---------------- L3: gates + fusion + MFMA out-projection + layernorm ----------------
// 16 graphs/block, 64 blocks. Reprs staged bf16 in LDS; gate dots per wave;
// pooled bf16 (stride 520 pad); outproj = 16x16x32 MFMA vs L2-resident Wt_out;
// LN epilogue from Es (aliased over dead repr region).
#define EM 16
__global__ __launch_bounds__(256) void fused_tail(
    const __bf16* __restrict__ r_mean, const __bf16* __restrict__ r_max, const __bf16* __restrict__ r_sum,
    const float* __restrict__ gwm, const float* __restrict__ gbm,
    const float* __restrict__ gwx, const float* __restrict__ gbx,
    const float* __restrict__ gws, const float* __restrict__ gbs,
    const __bf16* __restrict__ wtout, const float* __restrict__ bout,
    const float* __restrict__ gamma, const float* __restrict__ beta,
    float* __restrict__ out)
{
    int g0 = blockIdx.x * EM;
    int tid = threadIdx.x;
    int w = tid >> 6, lane = tid & 63;
    int qm = lane >> 4, rm = lane & 15;

    __shared__ __align__(16) char smem_raw[3*EM*HID*2];   // 48 KB: reprs, later Es
    __bf16 (*R3)[EM][HID] = (__bf16(*)[EM][HID])smem_raw; // R3[z][g][k]
    float (*Es)[264] = (float(*)[264])smem_raw;           // [16][264] f32 = 16.5 KB
    __shared__ __bf16 pooled[EM][520];                    // pad: b128 A-frags ~2-way
    __shared__ float wgt[EM][3];

    // stage reprs: 3*16*512 bf16 = 3072 bf16x8 chunks
    #pragma unroll
    for (int i = 0; i < 12; ++i) {
        int c = tid + i*256;
        int z = c >> 10, rem = c & 1023;
        int g = rem >> 6, kc = (rem & 63) * 8;
        const __bf16* src = (z==0) ? r_mean : (z==1) ? r_max : r_sum;
        *(bf16x8*)&R3[z][g][kc] = *(const bf16x8*)&src[(size_t)(g0 + g)*HID + kc];
    }
    __syncthreads();

    // gates: wave w -> graphs w*4 .. w*4+3
    float4 wm0 = *(const float4*)&gwm[lane*8], wm1 = *(const float4*)&gwm[lane*8+4];
    float4 wx0 = *(const float4*)&gwx[lane*8], wx1 = *(const float4*)&gwx[lane*8+4];
    float4 ws0 = *(const float4*)&gws[lane*8], ws1 = *(const float4*)&gws[lane*8+4];
    #pragma unroll
    for (int gi = 0; gi < 4; ++gi) {
        int g = w*4 + gi;
        bf16x8 am = *(const bf16x8*)&R3[0][g][lane*8];
        bf16x8 ax = *(const bf16x8*)&R3[1][g][lane*8];
        bf16x8 as = *(const bf16x8*)&R3[2][g][lane*8];
        float dm  = bdot8(am, wm0, wm1);
        float dx  = bdot8(ax, wx0, wx1);
        float dsv = bdot8(as, ws0, ws1);
        #pragma unroll
        for (int off = 32; off > 0; off >>= 1) {
            dm  += __shfl_xor(dm,  off, 64);
            dx  += __shfl_xor(dx,  off, 64);
            dsv += __shfl_xor(dsv, off, 64);
        }
        if (lane == 0) {
            float sm = 1.f/(1.f + expf(-(dm  + gbm[0])));
            float sx = 1.f/(1.f + expf(-(dx  + gbx[0])));
            float ss = 1.f/(1.f + expf(-(dsv + gbs[0])));
            float em = expf(sm), ex = expf(sx), es = expf(ss);
            float inv = 1.f/(em + ex + es);
            wgt[g][0] = em*inv; wgt[g][1] = ex*inv; wgt[g][2] = es*inv;
        }
    }
    __syncthreads();

    // pooled (bf16): 16*512 = 1024 bf16x8 chunks
    #pragma unroll
    for (int i = 0; i < 4; ++i) {
        int c = tid + i*256;
        int g = c >> 6, kc = (c & 63) * 8;
        bf16x8 am = *(const bf16x8*)&R3[0][g][kc];
        bf16x8 ax = *(const bf16x8*)&R3[1][g][kc];
        bf16x8 as = *(const bf16x8*)&R3[2][g][kc];
        float w0 = wgt[g][0], w1 = wgt[g][1], w2 = wgt[g][2];
        bf16x8 o;
        #pragma unroll
        for (int e = 0; e < 8; ++e)
            o[e] = (__bf16)(w0*(float)am[e] + w1*(float)ax[e] + w2*(float)as[e]);
        *(bf16x8*)&pooled[g][kc] = o;
    }
    __syncthreads();

    // out-projection: emb[16,256] = pooled[16,512] @ Wt_out^T, MFMA 16x16x32.
    // wave w covers n-tiles w*4 .. w*4+3.
    f32x4 ac0 = {0.f,0.f,0.f,0.f}, ac1 = ac0, ac2 = ac0, ac3 = ac0;
    const __bf16* Bt0 = wtout + (size_t)((w*4+0)*16 + rm)*HID;
    const __bf16* Bt1 = wtout + (size_t)((w*4+1)*16 + rm)*HID;
    const __bf16* Bt2 = wtout + (size_t)((w*4+2)*16 + rm)*HID;
    const __bf16* Bt3 = wtout + (size_t)((w*4+3)*16 + rm)*HID;
    #pragma unroll
    for (int kk = 0; kk < 16; ++kk) {
        int ko = kk*32 + qm*8;
        bf16x8 af = *(const bf16x8*)&pooled[rm][ko];
        ac0 = __builtin_amdgcn_mfma_f32_16x16x32_bf16(af, *(const bf16x8*)&Bt0[ko], ac0, 0, 0, 0);
        ac1 = __builtin_amdgcn_mfma_f32_16x16x32_bf16(af, *(const bf16x8*)&Bt1[ko], ac1, 0, 0, 0);
        ac2 = __builtin_amdgcn_mfma_f32_16x16x32_bf16(af, *(const bf16x8*)&Bt2[ko], ac2, 0, 0, 0);
        ac3 = __builtin_amdgcn_mfma_f32_16x16x32_bf16(af, *(const bf16x8*)&Bt3[ko], ac3, 0, 0, 0);
    }
    __syncthreads();   // R3 dead -> safe to alias as Es; all waves past pooled reads

    // C/D: col = lane&15 (n within tile), row = qm*4+reg (graph). Es[g][n] = acc + bout.
    float bo0 = bout[(w*4+0)*16 + rm], bo1 = bout[(w*4+1)*16 + rm];
    float bo2 = bout[(w*4+2)*16 + rm], bo3 = bout[(w*4+3)*16 + rm];
    #pragma unroll
    for (int r = 0; r < 4; ++r) {
        int g = qm*4 + r;
        Es[g][(w*4+0)*16 + rm] = ac0[r] + bo0;
        Es[g][(w*4+1)*16 + rm] = ac1[r] + bo1;
        Es[g][(w*4+2)*16 + rm] = ac2[r] + bo2;
        Es[g][(w*4+3)*16 + rm] = ac3[r] + bo3;
    }
    __syncthreads();

    // layernorm: wave w -> rows w*4 .. w*4+3; lane holds 4 consecutive cols
    float4 ga = *(const float4*)&gamma[lane*4];
    float4 be = *(const float4*)&beta[lane*4];
    #pragma unroll
    for (int i = 0; i < 4; ++i) {
        int g = w*4 + i;
        float4 v = *(const float4*)&Es[g][lane*4];
        float s  = (v.x + v.y) + (v.z + v.w);
        float sq = (v.x*v.x + v.y*v.y) + (v.z*v.z + v.w*v.w);
        #pragma unroll
        for (int off = 32; off > 0; off >>= 1) {
            s  += __shfl_xor(s,  off, 64);
            sq += __shfl_xor(sq, off, 64);
        }
        float mu  = s * (1.0f/IN_F);
        float var = sq * (1.0f/IN_F) - mu*mu;
        float rs  = rsqrtf(var + 1e-5f);
        float4 o;
        o.x = (v.x - mu)*rs*ga.x + be.x;
        o.y = (v.y - mu)*rs*ga.y + be.y;
        o.z = (v.z - mu)*rs*ga.z + be.z;
        o.w = (v.w - mu)*rs*ga.w + be.w;
        *(float4*)&out[(size_t)(g0 + g)*IN_F + lane*4] = o;
    }
}

extern "C" void kernel_launch(void* const* d_in, const int* in_sizes, int n_in,
                              void* d_out, int out_size, void* d_ws, size_t ws_size,
                              hipStream_t stream)
{
    const float* x        = (const float*)d_in[0];
    const int*   batch    = (const int*)d_in[1];
    const float* W_mean   = (const float*)d_in[2];
    const float* b_mean   = (const float*)d_in[3];
    const float* W_max    = (const float*)d_in[4];
    const float* b_max    = (const float*)d_in[5];
    const float* W_sum    = (const float*)d_in[6];
    const float* b_sum    = (const float*)d_in[7];
    const float* g_mean_w = (const float*)d_in[8];
    const float* g_mean_b = (const float*)d_in[9];
    const float* g_max_w  = (const float*)d_in[10];
    const float* g_max_b  = (const float*)d_in[11];
    const float* g_sum_w  = (const float*)d_in[12];
    const float* g_sum_b  = (const float*)d_in[13];
    const float* W_out    = (const float*)d_in[14];
    const float* b_out    = (const float*)d_in[15];
    const float* ln_gamma = (const float*)d_in[16];
    const float* ln_beta  = (const float*)d_in[17];
    float* out = (float*)d_out;
    int N = in_sizes[1];   // 200000 nodes

    // workspace layout (all bf16)
    __bf16* B = (__bf16*)d_ws;
    __bf16* pm    = B;                                   // [1024,256] x3
    __bf16* px    = pm  + (size_t)NUM_GRAPHS*IN_F;
    __bf16* psu   = px  + (size_t)NUM_GRAPHS*IN_F;
    __bf16* wtm   = psu + (size_t)NUM_GRAPHS*IN_F;       // [512,256] x3
    __bf16* wtx   = wtm + (size_t)HID*IN_F;
    __bf16* wts   = wtx + (size_t)HID*IN_F;
    __bf16* wtout = wts + (size_t)HID*IN_F;              // [256,512]
    __bf16* r_mean = wtout + (size_t)IN_F*HID;           // [1024,512] x3
    __bf16* r_max  = r_mean + (size_t)NUM_GRAPHS*HID;
    __bf16* r_sum  = r_max  + (size_t)NUM_GRAPHS*HID;

    pool_prep_kernel<<<NUM_GRAPHS + 128, 256, 0, stream>>>(
        x, batch, N, pm, px, psu,
        W_mean, W_max, W_sum, W_out, wtm, wtout);

    dim3 gridC(HID/64, NUM_GRAPHS/64, 3);   // (8,16,3) = 384 blocks
    transform_mfma<<<gridC, 256, 0, stream>>>(pm, px, psu, wtm, wtx, wts,
                                              b_mean, b_max, b_sum,
                                              r_mean, r_max, r_sum);

    fused_tail<<<NUM_GRAPHS/EM, 256, 0, stream>>>(r_mean, r_max, r_sum,
                                                  g_mean_w, g_mean_b, g_max_w, g_max_b,
                                                  g_sum_w, g_sum_b,
                                                  wtout, b_out, ln_gamma, ln_beta, out);
}

// Round 5
// 343.335 us; speedup vs baseline: 1.1922x; 1.0048x over previous
//
#include <hip/hip_runtime.h>
#include <math.h>

#define NUM_GRAPHS 1024
#define IN_F 256
#define HID 512

typedef __bf16 bf16x4 __attribute__((ext_vector_type(4)));
typedef __bf16 bf16x8 __attribute__((ext_vector_type(8)));
typedef float  f32x4  __attribute__((ext_vector_type(4)));

// Wave-cooperative lower_bound: 64 probes/round, 3 rounds for N=200000.
// Sorted input => pred is a lane-prefix; popc(ballot) locates the bracket.
__device__ __forceinline__ int wave_lower_bound(const int* __restrict__ b, int n, int v, int lane) {
    int lo = 0, hi = n;
    while (lo < hi) {
        int stride = (hi - lo + 63) >> 6;
        int idx = lo + lane * stride;
        bool pred = (idx < hi) && (b[idx] < v);
        unsigned long long bal = __ballot(pred);
        int cnt = __popcll(bal);
        int nhi = lo + cnt * stride;
        lo = (cnt == 0) ? lo : lo + (cnt - 1) * stride + 1;
        hi = (nhi < hi) ? nhi : hi;
    }
    return lo;
}

__device__ __forceinline__ float bdot8(bf16x8 a, float4 w0, float4 w1) {
    return (float)a[0]*w0.x + (float)a[1]*w0.y + (float)a[2]*w0.z + (float)a[3]*w0.w
         + (float)a[4]*w1.x + (float)a[5]*w1.y + (float)a[6]*w1.z + (float)a[7]*w1.w;
}

// ---------------- L1: pooling (blocks 0..1023) + W transposes (blocks 1024..1151) ----------------
__global__ __launch_bounds__(256) void pool_prep_kernel(
    const float* __restrict__ x, const int* __restrict__ batch, int N,
    __bf16* __restrict__ pool_mean, __bf16* __restrict__ pool_max,
    __bf16* __restrict__ pool_sum,
    const float* __restrict__ Wm, const float* __restrict__ Wx, const float* __restrict__ Wsm,
    const float* __restrict__ Wout,
    __bf16* __restrict__ wt,      // 3 x [512][256]
    __bf16* __restrict__ wtout)   // [256][512]
{
    if (blockIdx.x >= NUM_GRAPHS) {
        // ---- transpose role ----
        __shared__ float tile[64][65];
        int tb = blockIdx.x - NUM_GRAPHS;     // 0..127
        int z = tb >> 5, t = tb & 31;
        const float* S; __bf16* D; int SC, SR, r0, cb;
        if (z < 3) {
            S = (z==0) ? Wm : (z==1) ? Wx : Wsm;
            D = wt + (size_t)z * HID * IN_F;
            SR = 256; SC = 512;
            r0 = (t >> 3) * 64; cb = (t & 7) * 64;
        } else {
            S = Wout; D = wtout;
            SR = 512; SC = 256;
            r0 = (t >> 2) * 64; cb = (t & 3) * 64;
        }
        int r  = threadIdx.x >> 2;
        int c0 = (threadIdx.x & 3) * 16;
        #pragma unroll
        for (int j = 0; j < 4; ++j) {
            float4 v = *(const float4*)&S[(size_t)(r0 + r)*SC + cb + c0 + j*4];
            tile[r][c0+j*4+0] = v.x; tile[r][c0+j*4+1] = v.y;
            tile[r][c0+j*4+2] = v.z; tile[r][c0+j*4+3] = v.w;
        }
        __syncthreads();
        #pragma unroll
        for (int j = 0; j < 4; ++j) {
            bf16x4 o;
            o.x = (__bf16)tile[c0+j*4+0][r];
            o.y = (__bf16)tile[c0+j*4+1][r];
            o.z = (__bf16)tile[c0+j*4+2][r];
            o.w = (__bf16)tile[c0+j*4+3][r];
            *(bf16x4*)&D[(size_t)(cb + r)*SR + r0 + c0 + j*4] = o;
        }
        return;
    }
    // ---- pool role ----
    int g = blockIdx.x;
    int w = threadIdx.x >> 6, lane = threadIdx.x & 63;
    __shared__ int sb[2];
    if (w < 2) {                   // waves 0/1: parallel-probe search (3 rounds)
        int lb = wave_lower_bound(batch, N, g + w, lane);
        if (lane == 0) sb[w] = lb;
    }
    __syncthreads();
    int start = sb[0], end = sb[1];
    int cnt = end - start;
    const float4* x4 = (const float4*)x;
    float4 s = make_float4(0.f, 0.f, 0.f, 0.f);
    float4 m = make_float4(-INFINITY, -INFINITY, -INFINITY, -INFINITY);
    int r = start + w;
    for (; r + 12 < end; r += 16) {
        float4 v0 = x4[(size_t)(r     )*64 + lane];
        float4 v1 = x4[(size_t)(r +  4)*64 + lane];
        float4 v2 = x4[(size_t)(r +  8)*64 + lane];
        float4 v3 = x4[(size_t)(r + 12)*64 + lane];
        s.x += (v0.x+v1.x)+(v2.x+v3.x); s.y += (v0.y+v1.y)+(v2.y+v3.y);
        s.z += (v0.z+v1.z)+(v2.z+v3.z); s.w += (v0.w+v1.w)+(v2.w+v3.w);
        m.x = fmaxf(m.x, fmaxf(fmaxf(v0.x,v1.x), fmaxf(v2.x,v3.x)));
        m.y = fmaxf(m.y, fmaxf(fmaxf(v0.y,v1.y), fmaxf(v2.y,v3.y)));
        m.z = fmaxf(m.z, fmaxf(fmaxf(v0.z,v1.z), fmaxf(v2.z,v3.z)));
        m.w = fmaxf(m.w, fmaxf(fmaxf(v0.w,v1.w), fmaxf(v2.w,v3.w)));
    }
    for (; r < end; r += 4) {
        float4 v = x4[(size_t)r*64 + lane];
        s.x += v.x; s.y += v.y; s.z += v.z; s.w += v.w;
        m.x = fmaxf(m.x, v.x); m.y = fmaxf(m.y, v.y);
        m.z = fmaxf(m.z, v.z); m.w = fmaxf(m.w, v.w);
    }
    __shared__ float4 Ls[4][64];
    __shared__ float4 Lm[4][64];
    Ls[w][lane] = s; Lm[w][lane] = m;
    __syncthreads();
    if (w == 0) {
        float4 s0 = Ls[0][lane], s1 = Ls[1][lane], s2 = Ls[2][lane], s3 = Ls[3][lane];
        float4 m0 = Lm[0][lane], m1 = Lm[1][lane], m2 = Lm[2][lane], m3 = Lm[3][lane];
        float4 st, mt;
        st.x = (s0.x+s1.x)+(s2.x+s3.x); st.y = (s0.y+s1.y)+(s2.y+s3.y);
        st.z = (s0.z+s1.z)+(s2.z+s3.z); st.w = (s0.w+s1.w)+(s2.w+s3.w);
        mt.x = fmaxf(fmaxf(m0.x,m1.x), fmaxf(m2.x,m3.x));
        mt.y = fmaxf(fmaxf(m0.y,m1.y), fmaxf(m2.y,m3.y));
        mt.z = fmaxf(fmaxf(m0.z,m1.z), fmaxf(m2.z,m3.z));
        mt.w = fmaxf(fmaxf(m0.w,m1.w), fmaxf(m2.w,m3.w));
        float inv = 1.0f / fmaxf((float)cnt, 1.0f);
        if (cnt == 0) mt = make_float4(0.f, 0.f, 0.f, 0.f);
        bf16x4 sb4, mb4, xb4;
        sb4.x = (__bf16)st.x;       sb4.y = (__bf16)st.y;
        sb4.z = (__bf16)st.z;       sb4.w = (__bf16)st.w;
        mb4.x = (__bf16)(st.x*inv); mb4.y = (__bf16)(st.y*inv);
        mb4.z = (__bf16)(st.z*inv); mb4.w = (__bf16)(st.w*inv);
        xb4.x = (__bf16)mt.x;       xb4.y = (__bf16)mt.y;
        xb4.z = (__bf16)mt.z;       xb4.w = (__bf16)mt.w;
        size_t o = (size_t)g*64 + lane;
        ((bf16x4*)pool_sum)[o]  = sb4;
        ((bf16x4*)pool_mean)[o] = mb4;
        ((bf16x4*)pool_max)[o]  = xb4;
    }
}

// ---------------- L2: three transform GEMMs via bf16 MFMA, zero LDS, bf16 out ----------------
__global__ __launch_bounds__(256) void transform_mfma(
    const __bf16* __restrict__ pm, const __bf16* __restrict__ px, const __bf16* __restrict__ ps,
    const __bf16* __restrict__ wtm, const __bf16* __restrict__ wtx, const __bf16* __restrict__ wts,
    const float* __restrict__ bm_, const float* __restrict__ bx_, const float* __restrict__ bs_,
    __bf16* __restrict__ r_mean, __bf16* __restrict__ r_max, __bf16* __restrict__ r_sum)
{
    int z = blockIdx.z;
    const __bf16* A  = (z==0) ? pm  : (z==1) ? px  : ps;
    const __bf16* Bt = (z==0) ? wtm : (z==1) ? wtx : wts;
    const float* bias= (z==0) ? bm_ : (z==1) ? bx_ : bs_;
    __bf16* R        = (z==0) ? r_mean : (z==1) ? r_max : r_sum;

    int bn0 = blockIdx.x * 64;
    int bm0 = blockIdx.y * 64;
    int w = threadIdx.x >> 6, lane = threadIdx.x & 63;
    int qm = lane >> 4, rm = lane & 15;
    const bf16x8* Arow = (const bf16x8*)(A + (size_t)(bm0 + w*16 + rm)*IN_F);
    const bf16x8* B0 = (const bf16x8*)(Bt + (size_t)(bn0 +  0 + rm)*IN_F);
    const bf16x8* B1 = (const bf16x8*)(Bt + (size_t)(bn0 + 16 + rm)*IN_F);
    const bf16x8* B2 = (const bf16x8*)(Bt + (size_t)(bn0 + 32 + rm)*IN_F);
    const bf16x8* B3 = (const bf16x8*)(Bt + (size_t)(bn0 + 48 + rm)*IN_F);
    f32x4 a0 = {0.f,0.f,0.f,0.f}, a1 = a0, a2 = a0, a3 = a0;
    #pragma unroll
    for (int j = 0; j < 8; ++j) {
        int fi = j*4 + qm;
        bf16x8 af = Arow[fi];
        a0 = __builtin_amdgcn_mfma_f32_16x16x32_bf16(af, B0[fi], a0, 0, 0, 0);
        a1 = __builtin_amdgcn_mfma_f32_16x16x32_bf16(af, B1[fi], a1, 0, 0, 0);
        a2 = __builtin_amdgcn_mfma_f32_16x16x32_bf16(af, B2[fi], a2, 0, 0, 0);
        a3 = __builtin_amdgcn_mfma_f32_16x16x32_bf16(af, B3[fi], a3, 0, 0, 0);
    }
    int row0 = bm0 + w*16 + qm*4;
    float b0 = bias[bn0 +  0 + rm], b1 = bias[bn0 + 16 + rm];
    float b2 = bias[bn0 + 32 + rm], b3 = bias[bn0 + 48 + rm];
    #pragma unroll
    for (int r = 0; r < 4; ++r) {
        __bf16* Rr = R + (size_t)(row0 + r)*HID;
        Rr[bn0 +  0 + rm] = (__bf16)(a0[r] + b0);
        Rr[bn0 + 16 + rm] = (__bf16)(a1[r] + b1);
        Rr[bn0 + 32 + rm] = (__bf16)(a2[r] + b2);
        Rr[bn0 + 48 + rm] = (__bf16)(a3[r] + b3);
    }
}

// ---------------- L3: gates + fusion + MFMA out-projection + layernorm ----------------
#define EM 16
__global__ __launch_bounds__(256) void fused_tail(
    const __bf16* __restrict__ r_mean, const __bf16* __restrict__ r_max, const __bf16* __restrict__ r_sum,
    const float* __restrict__ gwm, const float* __restrict__ gbm,
    const float* __restrict__ gwx, const float* __restrict__ gbx,
    const float* __restrict__ gws, const float* __restrict__ gbs,
    const __bf16* __restrict__ wtout, const float* __restrict__ bout,
    const float* __restrict__ gamma, const float* __restrict__ beta,
    float* __restrict__ out)
{
    int g0 = blockIdx.x * EM;
    int tid = threadIdx.x;
    int w = tid >> 6, lane = tid & 63;
    int qm = lane >> 4, rm = lane & 15;

    __shared__ __align__(16) char smem_raw[3*EM*HID*2];   // 48 KB: reprs, later Es
    __bf16 (*R3)[EM][HID] = (__bf16(*)[EM][HID])smem_raw; // R3[z][g][k]
    float (*Es)[264] = (float(*)[264])smem_raw;           // [16][264] f32 = 16.5 KB
    __shared__ __bf16 pooled[EM][520];                    // pad: b128 A-frags ~2-way
    __shared__ float wgt[EM][3];

    #pragma unroll
    for (int i = 0; i < 12; ++i) {
        int c = tid + i*256;
        int z = c >> 10, rem = c & 1023;
        int g = rem >> 6, kc = (rem & 63) * 8;
        const __bf16* src = (z==0) ? r_mean : (z==1) ? r_max : r_sum;
        *(bf16x8*)&R3[z][g][kc] = *(const bf16x8*)&src[(size_t)(g0 + g)*HID + kc];
    }
    __syncthreads();

    float4 wm0 = *(const float4*)&gwm[lane*8], wm1 = *(const float4*)&gwm[lane*8+4];
    float4 wx0 = *(const float4*)&gwx[lane*8], wx1 = *(const float4*)&gwx[lane*8+4];
    float4 ws0 = *(const float4*)&gws[lane*8], ws1 = *(const float4*)&gws[lane*8+4];
    #pragma unroll
    for (int gi = 0; gi < 4; ++gi) {
        int g = w*4 + gi;
        bf16x8 am = *(const bf16x8*)&R3[0][g][lane*8];
        bf16x8 ax = *(const bf16x8*)&R3[1][g][lane*8];
        bf16x8 as = *(const bf16x8*)&R3[2][g][lane*8];
        float dm  = bdot8(am, wm0, wm1);
        float dx  = bdot8(ax, wx0, wx1);
        float dsv = bdot8(as, ws0, ws1);
        #pragma unroll
        for (int off = 32; off > 0; off >>= 1) {
            dm  += __shfl_xor(dm,  off, 64);
            dx  += __shfl_xor(dx,  off, 64);
            dsv += __shfl_xor(dsv, off, 64);
        }
        if (lane == 0) {
            float sm = 1.f/(1.f + expf(-(dm  + gbm[0])));
            float sx = 1.f/(1.f + expf(-(dx  + gbx[0])));
            float ss = 1.f/(1.f + expf(-(dsv + gbs[0])));
            float em = expf(sm), ex = expf(sx), es = expf(ss);
            float inv = 1.f/(em + ex + es);
            wgt[g][0] = em*inv; wgt[g][1] = ex*inv; wgt[g][2] = es*inv;
        }
    }
    __syncthreads();

    #pragma unroll
    for (int i = 0; i < 4; ++i) {
        int c = tid + i*256;
        int g = c >> 6, kc = (c & 63) * 8;
        bf16x8 am = *(const bf16x8*)&R3[0][g][kc];
        bf16x8 ax = *(const bf16x8*)&R3[1][g][kc];
        bf16x8 as = *(const bf16x8*)&R3[2][g][kc];
        float w0 = wgt[g][0], w1 = wgt[g][1], w2 = wgt[g][2];
        bf16x8 o;
        #pragma unroll
        for (int e = 0; e < 8; ++e)
            o[e] = (__bf16)(w0*(float)am[e] + w1*(float)ax[e] + w2*(float)as[e]);
        *(bf16x8*)&pooled[g][kc] = o;
    }
    __syncthreads();

    f32x4 ac0 = {0.f,0.f,0.f,0.f}, ac1 = ac0, ac2 = ac0, ac3 = ac0;
    const __bf16* Bt0 = wtout + (size_t)((w*4+0)*16 + rm)*HID;
    const __bf16* Bt1 = wtout + (size_t)((w*4+1)*16 + rm)*HID;
    const __bf16* Bt2 = wtout + (size_t)((w*4+2)*16 + rm)*HID;
    const __bf16* Bt3 = wtout + (size_t)((w*4+3)*16 + rm)*HID;
    #pragma unroll
    for (int kk = 0; kk < 16; ++kk) {
        int ko = kk*32 + qm*8;
        bf16x8 af = *(const bf16x8*)&pooled[rm][ko];
        ac0 = __builtin_amdgcn_mfma_f32_16x16x32_bf16(af, *(const bf16x8*)&Bt0[ko], ac0, 0, 0, 0);
        ac1 = __builtin_amdgcn_mfma_f32_16x16x32_bf16(af, *(const bf16x8*)&Bt1[ko], ac1, 0, 0, 0);
        ac2 = __builtin_amdgcn_mfma_f32_16x16x32_bf16(af, *(const bf16x8*)&Bt2[ko], ac2, 0, 0, 0);
        ac3 = __builtin_amdgcn_mfma_f32_16x16x32_bf16(af, *(const bf16x8*)&Bt3[ko], ac3, 0, 0, 0);
    }
    __syncthreads();   // R3 dead -> alias as Es

    float bo0 = bout[(w*4+0)*16 + rm], bo1 = bout[(w*4+1)*16 + rm];
    float bo2 = bout[(w*4+2)*16 + rm], bo3 = bout[(w*4+3)*16 + rm];
    #pragma unroll
    for (int r = 0; r < 4; ++r) {
        int g = qm*4 + r;
        Es[g][(w*4+0)*16 + rm] = ac0[r] + bo0;
        Es[g][(w*4+1)*16 + rm] = ac1[r] + bo1;
        Es[g][(w*4+2)*16 + rm] = ac2[r] + bo2;
        Es[g][(w*4+3)*16 + rm] = ac3[r] + bo3;
    }
    __syncthreads();

    float4 ga = *(const float4*)&gamma[lane*4];
    float4 be = *(const float4*)&beta[lane*4];
    #pragma unroll
    for (int i = 0; i < 4; ++i) {
        int g = w*4 + i;
        float4 v = *(const float4*)&Es[g][lane*4];
        float s  = (v.x + v.y) + (v.z + v.w);
        float sq = (v.x*v.x + v.y*v.y) + (v.z*v.z + v.w*v.w);
        #pragma unroll
        for (int off = 32; off > 0; off >>= 1) {
            s  += __shfl_xor(s,  off, 64);
            sq += __shfl_xor(sq, off, 64);
        }
        float mu  = s * (1.0f/IN_F);
        float var = sq * (1.0f/IN_F) - mu*mu;
        float rs  = rsqrtf(var + 1e-5f);
        float4 o;
        o.x = (v.x - mu)*rs*ga.x + be.x;
        o.y = (v.y - mu)*rs*ga.y + be.y;
        o.z = (v.z - mu)*rs*ga.z + be.z;
        o.w = (v.w - mu)*rs*ga.w + be.w;
        *(float4*)&out[(size_t)(g0 + g)*IN_F + lane*4] = o;
    }
}

extern "C" void kernel_launch(void* const* d_in, const int* in_sizes, int n_in,
                              void* d_out, int out_size, void* d_ws, size_t ws_size,
                              hipStream_t stream)
{
    const float* x        = (const float*)d_in[0];
    const int*   batch    = (const int*)d_in[1];
    const float* W_mean   = (const float*)d_in[2];
    const float* b_mean   = (const float*)d_in[3];
    const float* W_max    = (const float*)d_in[4];
    const float* b_max    = (const float*)d_in[5];
    const float* W_sum    = (const float*)d_in[6];
    const float* b_sum    = (const float*)d_in[7];
    const float* g_mean_w = (const float*)d_in[8];
    const float* g_mean_b = (const float*)d_in[9];
    const float* g_max_w  = (const float*)d_in[10];
    const float* g_max_b  = (const float*)d_in[11];
    const float* g_sum_w  = (const float*)d_in[12];
    const float* g_sum_b  = (const float*)d_in[13];
    const float* W_out    = (const float*)d_in[14];
    const float* b_out    = (const float*)d_in[15];
    const float* ln_gamma = (const float*)d_in[16];
    const float* ln_beta  = (const float*)d_in[17];
    float* out = (float*)d_out;
    int N = in_sizes[1];   // 200000 nodes

    // workspace layout (all bf16)
    __bf16* B = (__bf16*)d_ws;
    __bf16* pm    = B;                                   // [1024,256] x3
    __bf16* px    = pm  + (size_t)NUM_GRAPHS*IN_F;
    __bf16* psu   = px  + (size_t)NUM_GRAPHS*IN_F;
    __bf16* wtm   = psu + (size_t)NUM_GRAPHS*IN_F;       // [512,256] x3
    __bf16* wtx   = wtm + (size_t)HID*IN_F;
    __bf16* wts   = wtx + (size_t)HID*IN_F;
    __bf16* wtout = wts + (size_t)HID*IN_F;              // [256,512]
    __bf16* r_mean = wtout + (size_t)IN_F*HID;           // [1024,512] x3
    __bf16* r_max  = r_mean + (size_t)NUM_GRAPHS*HID;
    __bf16* r_sum  = r_max  + (size_t)NUM_GRAPHS*HID;

    pool_prep_kernel<<<NUM_GRAPHS + 128, 256, 0, stream>>>(
        x, batch, N, pm, px, psu,
        W_mean, W_max, W_sum, W_out, wtm, wtout);

    dim3 gridC(HID/64, NUM_GRAPHS/64, 3);   // (8,16,3) = 384 blocks
    transform_mfma<<<gridC, 256, 0, stream>>>(pm, px, psu, wtm, wtx, wts,
                                              b_mean, b_max, b_sum,
                                              r_mean, r_max, r_sum);

    fused_tail<<<NUM_GRAPHS/EM, 256, 0, stream>>>(r_mean, r_max, r_sum,
                                                  g_mean_w, g_mean_b, g_max_w, g_max_b,
                                                  g_sum_w, g_sum_b,
                                                  wtout, b_out, ln_gamma, ln_beta, out);
}